// Round 1
// baseline (34895.520 us; speedup 1.0000x reference)
//
#include <hip/hip_runtime.h>
#include <math.h>

// ---------------------------------------------------------------------------
// 2-layer LSTM, B=64 T=512 I=256 H=768, fp32 in/out.
// Strategy (round 1): graph-of-kernels. 513 pipelined step-kernels (layer 0 at
// step s, layer 1 at step s-1). Split-bf16 (hi+lo) MFMA for all GEMMs:
// product error ~2^-16, fp32 accumulation + fp32 gate math.
// Weights pre-permuted so output col p = 4*unit + gate (gate gather is local).
// ---------------------------------------------------------------------------

#define B_   64
#define T_   512
#define I_   256
#define H_   768
#define G4H  3072

constexpr size_t BTH = (size_t)B_ * T_ * H_;   // 25165824
constexpr size_t BH  = (size_t)B_ * H_;        // 49152

using bf16_t = __bf16;
using bf16x8 = __attribute__((ext_vector_type(8))) __bf16;
using f32x4  = __attribute__((ext_vector_type(4))) float;

#define MFMA16(a, b, c) __builtin_amdgcn_mfma_f32_16x16x32_bf16((a), (b), (c), 0, 0, 0)

// ---------------------------------------------------------------------------
// Prep: split fp32 weight into hi/lo bf16, permuting rows: p = 4*j + g where
// original row r = g*H + j. Row-major [3072][K].
__global__ void k_split(const float* __restrict__ src, bf16_t* __restrict__ hi,
                        bf16_t* __restrict__ lo, int K, int total) {
  int i = blockIdx.x * blockDim.x + threadIdx.x;
  int stride = gridDim.x * blockDim.x;
  for (; i < total; i += stride) {
    int p = i / K, k = i - p * K;
    int r = (p & 3) * H_ + (p >> 2);
    float w = src[(size_t)r * K + k];
    bf16_t h = (bf16_t)w;
    hi[i] = h;
    lo[i] = (bf16_t)(w - (float)h);
  }
}

__global__ void k_bias(const float* __restrict__ bih, const float* __restrict__ bhh,
                       float* __restrict__ bsum) {
  int p = blockIdx.x * blockDim.x + threadIdx.x;
  if (p < G4H) {
    int r = (p & 3) * H_ + (p >> 2);
    bsum[p] = bih[r] + bhh[r];
  }
}

__global__ void k_zero(int4* __restrict__ d, int n) {
  int i = blockIdx.x * blockDim.x + threadIdx.x;
  if (i < n) d[i] = make_int4(0, 0, 0, 0);
}

__device__ __forceinline__ float sigf(float v) { return 1.0f / (1.0f + expf(-v)); }

// One K=768 GEMM segment reading a split-bf16 activation ring [64][768] and a
// split-bf16 weight [3072][768]. A-frag: lane holds A[l&15][(l>>4)*8+e];
// B-frag: lane holds W[p(l&15)][(l>>4)*8+e]  (= B[k][n], n=permuted col).
__device__ __forceinline__ void seg_ring(
    const bf16_t* __restrict__ Ah, const bf16_t* __restrict__ Al,
    const bf16_t* __restrict__ Bh, const bf16_t* __restrict__ Bl,
    int arow, int koff, int p0, int p1, f32x4& acc0, f32x4& acc1) {
  const bf16_t* a_h = Ah + (size_t)arow * H_ + koff;
  const bf16_t* a_l = Al + (size_t)arow * H_ + koff;
  const bf16_t* b0h = Bh + (size_t)p0 * H_ + koff;
  const bf16_t* b0l = Bl + (size_t)p0 * H_ + koff;
  const bf16_t* b1h = Bh + (size_t)p1 * H_ + koff;
  const bf16_t* b1l = Bl + (size_t)p1 * H_ + koff;
#pragma unroll 4
  for (int kc = 0; kc < H_ / 32; ++kc) {
    bf16x8 ah  = *(const bf16x8*)(a_h + kc * 32);
    bf16x8 al  = *(const bf16x8*)(a_l + kc * 32);
    bf16x8 w0h = *(const bf16x8*)(b0h + kc * 32);
    bf16x8 w0l = *(const bf16x8*)(b0l + kc * 32);
    bf16x8 w1h = *(const bf16x8*)(b1h + kc * 32);
    bf16x8 w1l = *(const bf16x8*)(b1l + kc * 32);
    acc0 = MFMA16(ah, w0h, acc0);
    acc1 = MFMA16(ah, w1h, acc1);
    acc0 = MFMA16(al, w0h, acc0);
    acc1 = MFMA16(al, w1h, acc1);
    acc0 = MFMA16(ah, w0l, acc0);
    acc1 = MFMA16(ah, w1l, acc1);
  }
}

// Macro-step s: WGs 0..47 -> layer 0 step t=s (s<512); WGs 48..95 -> layer 1
// step t=s-1 (s>=1). Each WG owns 64 permuted cols (16 units) x all 64 batches.
// 8 waves: wave = (mtile = wave&3 -> rows 16m..16m+15, nh = wave>>2 -> 32 cols).
__launch_bounds__(512, 1)
__global__ void k_step(
    const float* __restrict__ x,
    const bf16_t* __restrict__ Wih0h, const bf16_t* __restrict__ Wih0l,
    const bf16_t* __restrict__ Whh0h, const bf16_t* __restrict__ Whh0l,
    const bf16_t* __restrict__ Wih1h, const bf16_t* __restrict__ Wih1l,
    const bf16_t* __restrict__ Whh1h, const bf16_t* __restrict__ Whh1l,
    const float* __restrict__ bsum0, const float* __restrict__ bsum1,
    bf16_t* __restrict__ h0hi, bf16_t* __restrict__ h0lo,
    bf16_t* __restrict__ h1hi, bf16_t* __restrict__ h1lo,
    float* __restrict__ c0, float* __restrict__ c1,
    float* __restrict__ out, int s) {
  const int wg = blockIdx.x;
  const int layer = (wg >= 48) ? 1 : 0;
  if (!layer && s >= T_) return;   // layer 0 runs s = 0..511
  if (layer && s == 0) return;     // layer 1 runs s = 1..512
  const int t = layer ? (s - 1) : s;
  const int wslice = layer ? (wg - 48) : wg;
  const int base_p = wslice * 64;  // permuted-col base (16 units)

  const int tid = threadIdx.x;
  const int wave = tid >> 6;
  const int lane = tid & 63;
  const int mtile = wave & 3;
  const int nh = wave >> 2;
  const int l15 = lane & 15;
  const int l4 = lane >> 4;
  const int koff = l4 * 8;
  const int arow = mtile * 16 + l15;
  const int p0 = base_p + nh * 32 + l15;
  const int p1 = p0 + 16;

  // 2-slot rings: h written at step t goes to slot t&1.
  const int slotR0 = (s + 1) & 1;  // h0_{s-1}
  const int slotW0 = s & 1;        // h0_s
  const int slotR1 = s & 1;        // h1_{s-2}
  const int slotW1 = (s + 1) & 1;  // h1_{s-1}

  f32x4 acc0 = {0.f, 0.f, 0.f, 0.f};
  f32x4 acc1 = {0.f, 0.f, 0.f, 0.f};

  if (!layer) {
    // seg0: x_t @ Wih0^T, K=256. x is fp32; split to hi/lo in-register.
    const float* xrow = x + ((size_t)arow * T_ + t) * I_;
    const bf16_t* b0h = Wih0h + (size_t)p0 * I_ + koff;
    const bf16_t* b0l = Wih0l + (size_t)p0 * I_ + koff;
    const bf16_t* b1h = Wih0h + (size_t)p1 * I_ + koff;
    const bf16_t* b1l = Wih0l + (size_t)p1 * I_ + koff;
#pragma unroll
    for (int kc = 0; kc < I_ / 32; ++kc) {
      const float* xp = xrow + kc * 32 + koff;
      float xv[8];
      *(float4*)(xv + 0) = *(const float4*)(xp + 0);
      *(float4*)(xv + 4) = *(const float4*)(xp + 4);
      bf16x8 ah, al;
#pragma unroll
      for (int e = 0; e < 8; ++e) {
        float v = xv[e];
        bf16_t hv = (bf16_t)v;
        ah[e] = hv;
        al[e] = (bf16_t)(v - (float)hv);
      }
      bf16x8 w0h = *(const bf16x8*)(b0h + kc * 32);
      bf16x8 w0l = *(const bf16x8*)(b0l + kc * 32);
      bf16x8 w1h = *(const bf16x8*)(b1h + kc * 32);
      bf16x8 w1l = *(const bf16x8*)(b1l + kc * 32);
      acc0 = MFMA16(ah, w0h, acc0);
      acc1 = MFMA16(ah, w1h, acc1);
      acc0 = MFMA16(al, w0h, acc0);
      acc1 = MFMA16(al, w1h, acc1);
      acc0 = MFMA16(ah, w0l, acc0);
      acc1 = MFMA16(ah, w1l, acc1);
    }
    // seg1: h0_{t-1} @ Whh0^T, K=768
    seg_ring(h0hi + (size_t)slotR0 * BH, h0lo + (size_t)slotR0 * BH,
             Whh0h, Whh0l, arow, koff, p0, p1, acc0, acc1);
  } else {
    // seg0: h0_t @ Wih1^T; seg1: h1_{t-1} @ Whh1^T
    seg_ring(h0hi + (size_t)slotR0 * BH, h0lo + (size_t)slotR0 * BH,
             Wih1h, Wih1l, arow, koff, p0, p1, acc0, acc1);
    seg_ring(h1hi + (size_t)slotR1 * BH, h1lo + (size_t)slotR1 * BH,
             Whh1h, Whh1l, arow, koff, p0, p1, acc0, acc1);
  }

  // C layout (verified m89): col = lane&15, row = (lane>>4)*4 + reg.
  // Transpose through LDS so each lane owns (batch, unit) with all 4 gates.
  __shared__ float pre[8][16][33];
#pragma unroll
  for (int r = 0; r < 4; ++r) {
    pre[wave][l4 * 4 + r][l15]      = acc0[r];
    pre[wave][l4 * 4 + r][16 + l15] = acc1[r];
  }
  __syncthreads();

  const float* bs = layer ? bsum1 : bsum0;
  float* cbuf = layer ? c1 : c0;
  const int b = mtile * 16 + l15;
#pragma unroll
  for (int k2 = 0; k2 < 2; ++k2) {
    const int u_loc = l4 + 4 * k2;          // 0..7 within this wave's 32 cols
    const int cl = 4 * u_loc;               // local col of gate i
    const int pg = base_p + 32 * nh + cl;   // global permuted col of gate i
    const int j = pg >> 2;                  // global hidden unit
    float ig = pre[wave][l15][cl + 0] + bs[pg + 0];
    float fg = pre[wave][l15][cl + 1] + bs[pg + 1];
    float gg = pre[wave][l15][cl + 2] + bs[pg + 2];
    float og = pre[wave][l15][cl + 3] + bs[pg + 3];
    ig = sigf(ig);
    fg = sigf(fg);
    gg = tanhf(gg);
    og = sigf(og);
    const size_t ci = (size_t)b * H_ + j;
    float cn = fg * cbuf[ci] + ig * gg;
    cbuf[ci] = cn;
    float h = og * tanhf(cn);
    bf16_t hh = (bf16_t)h;
    bf16_t hl = (bf16_t)(h - (float)hh);
    if (!layer) {
      h0hi[(size_t)slotW0 * BH + ci] = hh;
      h0lo[(size_t)slotW0 * BH + ci] = hl;
      if (t == T_ - 1) {
        out[BTH + ci] = h;            // h0 final
        out[BTH + 2 * BH + ci] = cn;  // c0 final
      }
    } else {
      h1hi[(size_t)slotW1 * BH + ci] = hh;
      h1lo[(size_t)slotW1 * BH + ci] = hl;
      out[(size_t)b * T_ * H_ + (size_t)t * H_ + j] = h;  // ys
      if (t == T_ - 1) {
        out[BTH + BH + ci] = h;       // h1 final
        out[BTH + 3 * BH + ci] = cn;  // c1 final
      }
    }
  }
}

// ---------------------------------------------------------------------------
extern "C" void kernel_launch(void* const* d_in, const int* in_sizes, int n_in,
                              void* d_out, int out_size, void* d_ws, size_t ws_size,
                              hipStream_t stream) {
  const float* x    = (const float*)d_in[0];
  const float* wih0 = (const float*)d_in[1];
  const float* whh0 = (const float*)d_in[2];
  const float* bih0 = (const float*)d_in[3];
  const float* bhh0 = (const float*)d_in[4];
  const float* wih1 = (const float*)d_in[5];
  const float* whh1 = (const float*)d_in[6];
  const float* bih1 = (const float*)d_in[7];
  const float* bhh1 = (const float*)d_in[8];
  float* out = (float*)d_out;

  char* base = (char*)d_ws;
  size_t off = 0;
  auto take = [&](size_t bytes) -> char* {
    char* r = base + off;
    off = (off + bytes + 255) & ~(size_t)255;
    return r;
  };
  bf16_t* Wih0h = (bf16_t*)take((size_t)G4H * I_ * 2);
  bf16_t* Wih0l = (bf16_t*)take((size_t)G4H * I_ * 2);
  bf16_t* Whh0h = (bf16_t*)take((size_t)G4H * H_ * 2);
  bf16_t* Whh0l = (bf16_t*)take((size_t)G4H * H_ * 2);
  bf16_t* Wih1h = (bf16_t*)take((size_t)G4H * H_ * 2);
  bf16_t* Wih1l = (bf16_t*)take((size_t)G4H * H_ * 2);
  bf16_t* Whh1h = (bf16_t*)take((size_t)G4H * H_ * 2);
  bf16_t* Whh1l = (bf16_t*)take((size_t)G4H * H_ * 2);
  float* bsum0 = (float*)take((size_t)G4H * 4);
  float* bsum1 = (float*)take((size_t)G4H * 4);
  // state block (zeroed each call): 4 ring arrays (2 slots each) + c0 + c1
  const size_t stateBytes = 4 * (2 * BH * 2) + 2 * (BH * 4);  // 1,179,648
  char* st = take(stateBytes);
  bf16_t* h0hi = (bf16_t*)st;
  bf16_t* h0lo = h0hi + 2 * BH;
  bf16_t* h1hi = h0lo + 2 * BH;
  bf16_t* h1lo = h1hi + 2 * BH;
  float* c0 = (float*)(h1lo + 2 * BH);
  float* c1 = c0 + BH;

  k_split<<<1024, 256, 0, stream>>>(wih0, Wih0h, Wih0l, I_, G4H * I_);
  k_split<<<2048, 256, 0, stream>>>(whh0, Whh0h, Whh0l, H_, G4H * H_);
  k_split<<<2048, 256, 0, stream>>>(wih1, Wih1h, Wih1l, H_, G4H * H_);
  k_split<<<2048, 256, 0, stream>>>(whh1, Whh1h, Whh1l, H_, G4H * H_);
  k_bias<<<12, 256, 0, stream>>>(bih0, bhh0, bsum0);
  k_bias<<<12, 256, 0, stream>>>(bih1, bhh1, bsum1);
  k_zero<<<(int)(stateBytes / 16 + 255) / 256, 256, 0, stream>>>((int4*)st,
                                                                 (int)(stateBytes / 16));
  for (int s = 0; s <= T_; ++s) {
    k_step<<<96, 512, 0, stream>>>(x, Wih0h, Wih0l, Whh0h, Whh0l, Wih1h, Wih1l,
                                   Whh1h, Whh1l, bsum0, bsum1, h0hi, h0lo, h1hi,
                                   h1lo, c0, c1, out, s);
  }
}

// Round 2
// 5144.044 us; speedup vs baseline: 6.7837x; 6.7837x over previous
//
#include <hip/hip_runtime.h>
#include <math.h>

// ---------------------------------------------------------------------------
// 2-layer LSTM, B=64 T=512 I=256 H=768, fp32 in/out.
// Round 2: fp16 single-precision MFMA (16x16x32_f16), all operands pre-packed
// into MFMA fragment-major layout so every global load is a coalesced
// 16B/lane dwordx4. 513 pipelined step kernels, 192 WGs (96 col-slices of
// 32 cols per layer), 8 waves = 2 mgroups x 4 kgroups, 2x2 register tile,
// LDS reduction over kgroups.
// ---------------------------------------------------------------------------

#define B_   64
#define T_   512
#define I_   256
#define H_   768
#define G4H  3072
#define NW   96    // col-slices per layer (32 permuted cols each)

constexpr size_t BTH = (size_t)B_ * T_ * H_;   // 25165824
constexpr size_t BH  = (size_t)B_ * H_;        // 49152

using f16_t = _Float16;
using f16x8 = __attribute__((ext_vector_type(8))) _Float16;
using f32x4 = __attribute__((ext_vector_type(4))) float;

#define MFMA(a, b, c) __builtin_amdgcn_mfma_f32_16x16x32_f16((a), (b), (c), 0, 0, 0)

// ---------------------------------------------------------------------------
// Pack fp32 weight [4H][K] (gate-major rows) into fp16 fragment-major:
// Wf[ptile][kc][lane][e]: p = ptile*16 + (lane&15) (permuted col: p = 4*unit+gate),
// k = kc*32 + (lane>>4)*8 + e, original row r = (p&3)*H + (p>>2).
__global__ void k_packW(const float* __restrict__ src, f16_t* __restrict__ dst,
                        int K, int KC, int total) {
  int i = blockIdx.x * blockDim.x + threadIdx.x;
  int stride = gridDim.x * blockDim.x;
  for (; i < total; i += stride) {
    int e = i & 7;
    int lane = (i >> 3) & 63;
    int rest = i >> 9;          // ptile*KC + kc
    int kc = rest % KC;
    int ptile = rest / KC;
    int p = ptile * 16 + (lane & 15);
    int k = kc * 32 + (lane >> 4) * 8 + e;
    int r = (p & 3) * H_ + (p >> 2);
    dst[i] = (f16_t)src[(size_t)r * K + k];
  }
}

// Pack x [64][512][256] fp32 -> Xf[mtile(4)][t(512)][kc(8)][lane(64)][e(8)] fp16.
__global__ void k_packX(const float* __restrict__ x, f16_t* __restrict__ dst) {
  int i = blockIdx.x * blockDim.x + threadIdx.x;
  int stride = gridDim.x * blockDim.x;
  const int total = 4 * T_ * 8 * 64 * 8;  // 8,388,608
  for (; i < total; i += stride) {
    int e = i & 7;
    int lane = (i >> 3) & 63;
    int kc = (i >> 9) & 7;
    int t = (i >> 12) & 511;
    int mtile = i >> 21;
    int b = mtile * 16 + (lane & 15);
    int k = kc * 32 + (lane >> 4) * 8 + e;
    dst[i] = (f16_t)x[((size_t)b * T_ + t) * I_ + k];
  }
}

__global__ void k_bias(const float* __restrict__ bih, const float* __restrict__ bhh,
                       float* __restrict__ bsum) {
  int p = blockIdx.x * blockDim.x + threadIdx.x;
  if (p < G4H) {
    int r = (p & 3) * H_ + (p >> 2);
    bsum[p] = bih[r] + bhh[r];
  }
}

__global__ void k_zero(int4* __restrict__ d, int n) {
  int i = blockIdx.x * blockDim.x + threadIdx.x;
  if (i < n) d[i] = make_int4(0, 0, 0, 0);
}

__device__ __forceinline__ float sigf(float v) { return 1.0f / (1.0f + expf(-v)); }

// ---------------------------------------------------------------------------
// Macro-step s: WGs 0..95 -> layer 0 (t=s, s<512); 96..191 -> layer 1 (t=s-1,
// s>=1). WG owns 32 permuted cols (8 units) x 64 batch. 8 waves = mg(2) x kg(4);
// wave computes 2 mtiles x 2 ptiles partial sums over its k-range.
// h rings stored fp16 fragment-major: [slot][mtile(4)][kc(24)][lane(64)][e(8)].
__launch_bounds__(512, 1)
__global__ void k_step(
    const f16_t* __restrict__ Xf,
    const f16_t* __restrict__ Wih0f, const f16_t* __restrict__ Whh0f,
    const f16_t* __restrict__ Wih1f, const f16_t* __restrict__ Whh1f,
    const float* __restrict__ bsum0, const float* __restrict__ bsum1,
    f16_t* __restrict__ h0f, f16_t* __restrict__ h1f,
    float* __restrict__ c0, float* __restrict__ c1,
    float* __restrict__ out, int s) {
  const int wg = blockIdx.x;
  const int layer = wg >= NW;
  if (!layer && s >= T_) return;
  if (layer && s == 0) return;
  const int t = layer ? (s - 1) : s;
  const int ws = layer ? (wg - NW) : wg;

  const int tid = threadIdx.x;
  const int wave = tid >> 6, lane = tid & 63;
  const int mg = wave & 1, kg = wave >> 1;
  const int l15 = lane & 15, l4 = lane >> 4;
  const int laneo = lane * 8;

  const int slotR0 = (s + 1) & 1, slotW0 = s & 1;
  const int slotR1 = s & 1,       slotW1 = (s + 1) & 1;

  const int pt0 = ws * 2, pt1 = ws * 2 + 1;
  const int m0 = mg * 2, m1 = mg * 2 + 1;

  f32x4 acc00 = {0.f, 0.f, 0.f, 0.f}, acc01 = {0.f, 0.f, 0.f, 0.f};
  f32x4 acc10 = {0.f, 0.f, 0.f, 0.f}, acc11 = {0.f, 0.f, 0.f, 0.f};

  // h frag strides: slot 49152, mtile 12288, kc 512.
  auto run_seg = [&](const f16_t* a0p, const f16_t* a1p,
                     const f16_t* W, int KC, int kc0, int n) {
    const f16_t* w0p = W + ((size_t)pt0 * KC + kc0) * 512 + laneo;
    const f16_t* w1p = W + ((size_t)pt1 * KC + kc0) * 512 + laneo;
#pragma unroll 4
    for (int i = 0; i < n; ++i) {
      f16x8 a0 = *(const f16x8*)a0p; a0p += 512;
      f16x8 a1 = *(const f16x8*)a1p; a1p += 512;
      f16x8 w0 = *(const f16x8*)w0p; w0p += 512;
      f16x8 w1 = *(const f16x8*)w1p; w1p += 512;
      acc00 = MFMA(a0, w0, acc00);
      acc01 = MFMA(a0, w1, acc01);
      acc10 = MFMA(a1, w0, acc10);
      acc11 = MFMA(a1, w1, acc11);
    }
  };

  if (!layer) {
    if (kg == 0) {
      // x_t @ Wih0^T : K=256 (8 chunks), Xf[mtile][t] block = 4096 elems
      const f16_t* a0p = Xf + ((size_t)m0 * T_ + t) * 4096 + laneo;
      const f16_t* a1p = Xf + ((size_t)m1 * T_ + t) * 4096 + laneo;
      run_seg(a0p, a1p, Wih0f, 8, 0, 8);
    } else {
      // h0_{t-1} @ Whh0^T : chunks (kg-1)*8 .. +8 of 24
      const int kcs = (kg - 1) * 8;
      const f16_t* base = h0f + (size_t)slotR0 * 49152 + (size_t)kcs * 512 + laneo;
      run_seg(base + (size_t)m0 * 12288, base + (size_t)m1 * 12288, Whh0f, 24, kcs, 8);
    }
  } else {
    if (kg < 2) {
      // h0_t @ Wih1^T : chunks kg*12 .. +12
      const int kcs = kg * 12;
      const f16_t* base = h0f + (size_t)slotR0 * 49152 + (size_t)kcs * 512 + laneo;
      run_seg(base + (size_t)m0 * 12288, base + (size_t)m1 * 12288, Wih1f, 24, kcs, 12);
    } else {
      // h1_{t-1} @ Whh1^T : chunks (kg-2)*12 .. +12
      const int kcs = (kg - 2) * 12;
      const f16_t* base = h1f + (size_t)slotR1 * 49152 + (size_t)kcs * 512 + laneo;
      run_seg(base + (size_t)m0 * 12288, base + (size_t)m1 * 12288, Whh1f, 24, kcs, 12);
    }
  }

  // Partial-sum exchange. C layout (verified): col = lane&15, row = l4*4+reg.
  __shared__ float pre[4][64][33];
#pragma unroll
  for (int r = 0; r < 4; ++r) {
    pre[kg][m0 * 16 + l4 * 4 + r][l15]      = acc00[r];
    pre[kg][m0 * 16 + l4 * 4 + r][16 + l15] = acc01[r];
    pre[kg][m1 * 16 + l4 * 4 + r][l15]      = acc10[r];
    pre[kg][m1 * 16 + l4 * 4 + r][16 + l15] = acc11[r];
  }
  __syncthreads();

  // Gate phase: thread = (unit u 0..7, batch b 0..63).
  const int u = tid >> 6;
  const int b = tid & 63;
  const float* bs = layer ? bsum1 : bsum0;
  float* cbuf = layer ? c1 : c0;
  const int pg = ws * 32 + 4 * u;   // permuted col of gate i
  const int j = ws * 8 + u;         // global hidden unit
  const int cl = 4 * u;
  float g0 = pre[0][b][cl + 0] + pre[1][b][cl + 0] + pre[2][b][cl + 0] + pre[3][b][cl + 0] + bs[pg + 0];
  float g1 = pre[0][b][cl + 1] + pre[1][b][cl + 1] + pre[2][b][cl + 1] + pre[3][b][cl + 1] + bs[pg + 1];
  float g2 = pre[0][b][cl + 2] + pre[1][b][cl + 2] + pre[2][b][cl + 2] + pre[3][b][cl + 2] + bs[pg + 2];
  float g3 = pre[0][b][cl + 3] + pre[1][b][cl + 3] + pre[2][b][cl + 3] + pre[3][b][cl + 3] + bs[pg + 3];
  float ig = sigf(g0), fg = sigf(g1), gg = tanhf(g2), og = sigf(g3);
  const size_t ci = (size_t)b * H_ + j;
  float cn = fg * cbuf[ci] + ig * gg;
  cbuf[ci] = cn;
  float h = og * tanhf(cn);

  // Store h into fp16 fragment ring: [slot][b>>4][j>>5][((j>>3)&3)*16 + (b&15)][j&7]
  const int lblk = ((j >> 3) & 3) * 16 + (b & 15);
  const size_t hidx =
      ((((size_t)(layer ? slotW1 : slotW0) * 4 + (b >> 4)) * 24 + (j >> 5)) * 64 + lblk) * 8 + (j & 7);
  if (!layer) {
    h0f[hidx] = (f16_t)h;
    if (t == T_ - 1) {
      out[BTH + ci] = h;             // h0 final
      out[BTH + 2 * BH + ci] = cn;   // c0 final
    }
  } else {
    h1f[hidx] = (f16_t)h;
    out[((size_t)b * T_ + t) * H_ + j] = h;  // ys
    if (t == T_ - 1) {
      out[BTH + BH + ci] = h;        // h1 final
      out[BTH + 3 * BH + ci] = cn;   // c1 final
    }
  }
}

// ---------------------------------------------------------------------------
extern "C" void kernel_launch(void* const* d_in, const int* in_sizes, int n_in,
                              void* d_out, int out_size, void* d_ws, size_t ws_size,
                              hipStream_t stream) {
  const float* x    = (const float*)d_in[0];
  const float* wih0 = (const float*)d_in[1];
  const float* whh0 = (const float*)d_in[2];
  const float* bih0 = (const float*)d_in[3];
  const float* bhh0 = (const float*)d_in[4];
  const float* wih1 = (const float*)d_in[5];
  const float* whh1 = (const float*)d_in[6];
  const float* bih1 = (const float*)d_in[7];
  const float* bhh1 = (const float*)d_in[8];
  float* out = (float*)d_out;

  char* base = (char*)d_ws;
  size_t off = 0;
  auto take = [&](size_t bytes) -> char* {
    char* r = base + off;
    off = (off + bytes + 255) & ~(size_t)255;
    return r;
  };
  f16_t* Wih0f = (f16_t*)take((size_t)G4H * I_ * 2);
  f16_t* Whh0f = (f16_t*)take((size_t)G4H * H_ * 2);
  f16_t* Wih1f = (f16_t*)take((size_t)G4H * H_ * 2);
  f16_t* Whh1f = (f16_t*)take((size_t)G4H * H_ * 2);
  f16_t* Xf    = (f16_t*)take((size_t)4 * T_ * 8 * 64 * 8 * 2);
  float* bsum0 = (float*)take((size_t)G4H * 4);
  float* bsum1 = (float*)take((size_t)G4H * 4);
  // state: h0f/h1f rings (2 slots x 49152 f16) + c0/c1 (49152 f32 each)
  const size_t stateBytes = 2 * (2 * 49152 * 2) + 2 * (BH * 4);  // 786432
  char* st = take(stateBytes);
  f16_t* h0f = (f16_t*)st;
  f16_t* h1f = h0f + 2 * 49152;
  float* c0 = (float*)(h1f + 2 * 49152);
  float* c1 = c0 + BH;

  k_packW<<<768, 256, 0, stream>>>(wih0, Wih0f, I_, 8, G4H * I_);
  k_packW<<<2048, 256, 0, stream>>>(whh0, Whh0f, H_, 24, G4H * H_);
  k_packW<<<2048, 256, 0, stream>>>(wih1, Wih1f, H_, 24, G4H * H_);
  k_packW<<<2048, 256, 0, stream>>>(whh1, Whh1f, H_, 24, G4H * H_);
  k_packX<<<4096, 256, 0, stream>>>(x, Xf);
  k_bias<<<12, 256, 0, stream>>>(bih0, bhh0, bsum0);
  k_bias<<<12, 256, 0, stream>>>(bih1, bhh1, bsum1);
  k_zero<<<192, 256, 0, stream>>>((int4*)st, (int)(stateBytes / 16));

  for (int s = 0; s <= T_; ++s) {
    k_step<<<192, 512, 0, stream>>>(Xf, Wih0f, Whh0f, Wih1f, Whh1f, bsum0, bsum1,
                                    h0f, h1f, c0, c1, out, s);
  }
}